// Round 3
// baseline (146.887 us; speedup 1.0000x reference)
//
#include <hip/hip_runtime.h>
#include <math.h>

#define HW   512
#define IMG  (512 * 512)
#define NB   64
#define SR   16                                  // strip rows per block
#define BLOCK 256
#define WAVES_PER_BLOCK (BLOCK / 64)             // 4
#define STRIPS_PER_IMG (HW / SR)                 // 32
#define NBLOCKS (NB * STRIPS_PER_IMG)            // 2048

__device__ __forceinline__ void unpack8(const float4& q0, const float4& q1, float* a) {
    a[0] = q0.x; a[1] = q0.y; a[2] = q0.z; a[3] = q0.w;
    a[4] = q1.x; a[5] = q1.y; a[6] = q1.z; a[7] = q1.w;
}

// Async global->LDS, 16B per lane. Destination is LDS base + lane*16 (linear),
// source is the per-lane global pointer. No VGPR payload -> unlimited MLP.
__device__ __forceinline__ void gload_lds16(const float* g, float* l) {
    __builtin_amdgcn_global_load_lds(
        (const __attribute__((address_space(1))) void*)g,
        (__attribute__((address_space(3))) void*)l,
        16, 0, 0);
}

// Strategy: VGPR-destined loads were serialized by register-budget limits
// (R1/R2: VGPR 36->60, dur unchanged). Here ALL bulk traffic is staged via
// global_load_lds (64 KB/block in flight, one drain point), halo rows via 2
// small VGPR loads on edge waves. launch_bounds(256,2): LDS is the occupancy
// limiter (2 blocks/CU); give the allocator a 256-VGPR budget so nothing sinks.
__global__ __launch_bounds__(BLOCK, 2) void eik_main(const float* __restrict__ pred,
                                                     const float* __restrict__ reach,
                                                     float* __restrict__ partials) {
    const int lane = threadIdx.x & 63;
    const int w    = threadIdx.x >> 6;           // wave id 0..3
    const int strip = blockIdx.x & (STRIPS_PER_IMG - 1);
    const int b     = blockIdx.x >> 5;
    const int y0    = strip * SR;

    __shared__ float smem[2 * SR * HW];          // 64 KB: pred rows [0,8192), reach rows [8192,16384)

    const float* pbase = pred  + (size_t)b * IMG + (size_t)y0 * HW;
    const float* rbase = reach + (size_t)b * IMG + (size_t)y0 * HW;

    // Halo rows (strip row -1 and SR), edge-clamped at image boundary.
    // Only waves 0 and 3 need them; issue these VGPR loads first.
    float4 H0 = {}, H1 = {};
    if (w == 0) {
        const int hy = (y0 == 0) ? 0 : -1;
        const float* hp = pbase + hy * HW + (lane << 3);
        H0 = *(const float4*)hp;
        H1 = *(const float4*)(hp + 4);
    }
    if (w == 3) {
        const int hy = (y0 + SR > HW - 1) ? (SR - 1) : SR;
        const float* hp = pbase + hy * HW + (lane << 3);
        H0 = *(const float4*)hp;
        H1 = *(const float4*)(hp + 4);
    }

    // Stage 64 x 1KB units: pred rows 0..15 (units 0..31), reach rows 0..15
    // (units 32..63). Each wave issues 16 back-to-back async loads.
#pragma unroll
    for (int k = 0; k < 16; ++k) {
        const int u = (w << 4) | k;
        const float* src = (u < 32)
            ? pbase + (size_t)(u >> 1) * HW        + ((u & 1) << 8) + (lane << 2)
            : rbase + (size_t)((u - 32) >> 1) * HW + ((u & 1) << 8) + (lane << 2);
        gload_lds16(src, smem + u * 256);
    }

    __syncthreads();   // drains vmcnt(0): all staging + halo loads complete

    // Each wave computes 4 output rows r0..r0+3 of the strip.
    const int r0 = w << 2;
    float4 P[6][2];
    float4 R[4][2];
#pragma unroll
    for (int j = 0; j < 6; ++j) {
        int sr = r0 - 1 + j;
        sr = sr < 0 ? 0 : (sr > SR - 1 ? SR - 1 : sr);
        const float* p = smem + sr * HW + (lane << 3);
        P[j][0] = *(const float4*)p;
        P[j][1] = *(const float4*)(p + 4);
    }
#pragma unroll
    for (int t = 0; t < 4; ++t) {
        const float* p = smem + SR * HW + (r0 + t) * HW + (lane << 3);
        R[t][0] = *(const float4*)p;
        R[t][1] = *(const float4*)(p + 4);
    }
    if (w == 0) { P[0][0] = H0; P[0][1] = H1; }   // strip row -1 (image halo)
    if (w == 3) { P[5][0] = H0; P[5][1] = H1; }   // strip row SR (image halo)

    float vsum = 0.0f, csum = 0.0f;

#pragma unroll
    for (int t = 0; t < 4; ++t) {
        float am[8], a0[8], ap[8], rv[8];
        unpack8(P[t][0],     P[t][1],     am);
        unpack8(P[t + 1][0], P[t + 1][1], a0);
        unpack8(P[t + 2][0], P[t + 2][1], ap);
        unpack8(R[t][0],     R[t][1],     rv);

        // separable Sobel: S = vertical [1,2,1], D = vertical [-1,0,1]
        float s[8], d[8];
#pragma unroll
        for (int i = 0; i < 8; ++i) {
            s[i] = am[i] + 2.0f * a0[i] + ap[i];
            d[i] = ap[i] - am[i];
        }

        float sl = __shfl_up(s[7], 1, 64);
        float dl = __shfl_up(d[7], 1, 64);
        float sr = __shfl_down(s[0], 1, 64);
        float dr = __shfl_down(d[0], 1, 64);
        if (lane == 0)  { sl = s[0]; dl = d[0]; }
        if (lane == 63) { sr = s[7]; dr = d[7]; }

        const float S[10] = {sl, s[0], s[1], s[2], s[3], s[4], s[5], s[6], s[7], sr};
        const float D[10] = {dl, d[0], d[1], d[2], d[3], d[4], d[5], d[6], d[7], dr};

#pragma unroll
        for (int i = 0; i < 8; ++i) {
            const float gx = (S[i+2] - S[i]) * 0.125f;
            const float gy = (D[i] + 2.0f * D[i+1] + D[i+2]) * 0.125f;
            const float mag  = __builtin_amdgcn_sqrtf(gx * gx + gy * gy + 1e-8f);
            const float viol = fabsf(mag - 1.0f);
            const bool  m    = rv[i] > 0.5f;
            vsum += m ? viol : 0.0f;
            csum += m ? 1.0f : 0.0f;
        }
    }

    // wave-64 reduction
#pragma unroll
    for (int off = 32; off > 0; off >>= 1) {
        vsum += __shfl_down(vsum, off, 64);
        csum += __shfl_down(csum, off, 64);
    }

    __shared__ float sv[WAVES_PER_BLOCK];
    __shared__ float sc[WAVES_PER_BLOCK];
    if (lane == 0) { sv[w] = vsum; sc[w] = csum; }
    __syncthreads();
    if (threadIdx.x == 0) {
        partials[2 * blockIdx.x]     = sv[0] + sv[1] + sv[2] + sv[3];
        partials[2 * blockIdx.x + 1] = sc[0] + sc[1] + sc[2] + sc[3];
    }
}

__global__ __launch_bounds__(BLOCK) void eik_finalize(const float* __restrict__ partials,
                                                      float* __restrict__ out) {
    float v = 0.0f, c = 0.0f;
    for (int i = threadIdx.x; i < NBLOCKS; i += BLOCK) {
        v += partials[2 * i];
        c += partials[2 * i + 1];
    }
#pragma unroll
    for (int off = 32; off > 0; off >>= 1) {
        v += __shfl_down(v, off, 64);
        c += __shfl_down(c, off, 64);
    }
    __shared__ float sv[WAVES_PER_BLOCK];
    __shared__ float sc[WAVES_PER_BLOCK];
    const int lane = threadIdx.x & 63;
    const int wid  = threadIdx.x >> 6;
    if (lane == 0) { sv[wid] = v; sc[wid] = c; }
    __syncthreads();
    if (threadIdx.x == 0) {
        const float vt = sv[0] + sv[1] + sv[2] + sv[3];
        const float ct = sc[0] + sc[1] + sc[2] + sc[3];
        out[0] = vt / fmaxf(ct, 1.0f);
    }
}

extern "C" void kernel_launch(void* const* d_in, const int* in_sizes, int n_in,
                              void* d_out, int out_size, void* d_ws, size_t ws_size,
                              hipStream_t stream) {
    const float* pred  = (const float*)d_in[0];
    const float* reach = (const float*)d_in[1];
    float* out = (float*)d_out;
    float* ws  = (float*)d_ws;

    eik_main<<<NBLOCKS, BLOCK, 0, stream>>>(pred, reach, ws);
    eik_finalize<<<1, BLOCK, 0, stream>>>(ws, out);
}